// Round 2
// baseline (342.719 us; speedup 1.0000x reference)
//
#include <hip/hip_runtime.h>

// Round 11: cooperative fusion, hardened.
//   - Slimmed LDS (25.8 KB: sXt + sB + sH + vec) -> capacity margin. C's
//     A-operand frags live in 8 VGPRs (loaded from L2-hot fp32 Cm in phase C)
//     instead of an 8 KB sC tile.
//   - Hand-rolled grid barrier (device-scope atomics + threadfence, counters
//     in ws, zeroed per launch) -- does not rely on cg::this_grid().sync().
//     hipLaunchCooperativeKernel used ONLY for the residency guarantee.
//   - If the cooperative launch is rejected (capacity/capture), fall back to
//     the proven round-9 three-kernel path (passed at 97 us).
// Phases (fused path):
//   A: per (b,h,c) block stage sXt (X^T swz), B^T swz -> sH, B[t][n] swz -> sB,
//      cumsum vectors -> sVec/sWf (all persist in LDS); MFMA Hend0=(w.X)^T.B;
//      restage Hend into sH; dump 8KB to Hbuf. Only Hbuf+Dchunk touch global.
//   grid barrier
//   B: 32-chunk scan over bf16 pairs (wave 0 of each block, 65536 threads,
//      two 16-chunk batches to halve VGPR pressure). Hstart in-place + Hlast.
//   grid barrier
//   C: DMA Hstart->sH; load C frags (regs); G=C.B^T; S=mask*exp*G (alias over
//      sB); Y = S.Xt + Lam*(C.Hstart), single store.
// Tile format: 64x64 bf16, UNPADDED, 16B-group XOR swizzle:
//   elem(row,col) at row*64 + ((col>>3 ^ (row&7))<<3) + (col&7).
// MFMA 16x16x32 bf16: A m=lane&15,k=quad*8+j; B n=lane&15,k=quad*8+j;
//                     D col=lane&15, row=quad*4+reg.
// All MFMA frag rows are == l16 (mod 8), so swizzle group = (ko>>3)^(l16&7).

constexpr int BSZ = 2, T = 2048, H = 16, P = 64, N = 64;
constexpr int L = 64, NC = T / L;   // 32 chunks
constexpr int NBLK = BSZ * NC * H;  // 1024
constexpr int LSB = 72;             // fallback-KA-internal padded stride

using bf16x8 = __attribute__((ext_vector_type(8))) short;
using f32x4  = __attribute__((ext_vector_type(4))) float;

__device__ inline ushort f2bf(float f) {
    unsigned u = __float_as_uint(f);
    u += 0x7FFFu + ((u >> 16) & 1u);
    return (ushort)(u >> 16);
}
__device__ inline unsigned pack2(float a, float b) {
    return (unsigned)f2bf(a) | ((unsigned)f2bf(b) << 16);
}
__device__ inline float bf2f(ushort h) {
    return __uint_as_float(((unsigned)h) << 16);
}
__device__ inline int swz(int row, int col) {   // element offset in 64x64 tile
    return row * 64 + ((((col >> 3) ^ (row & 7))) << 3) + (col & 7);
}

typedef __attribute__((address_space(3))) unsigned int       lds_u32;
typedef const __attribute__((address_space(1))) unsigned int glb_u32;
__device__ inline void dma16(const void* g, void* l) {   // 16B/lane -> 1KB/wave
    __builtin_amdgcn_global_load_lds((glb_u32*)g, (lds_u32*)l, 16, 0, 0);
}
__device__ inline void dma4(const void* g, void* l) {
    __builtin_amdgcn_global_load_lds((glb_u32*)g, (lds_u32*)l, 4, 0, 0);
}

// Hand-rolled grid barrier. cnt/gate zeroed host-side before each launch.
// Release: __syncthreads drains every wave's stores to L2; thread0's
// __threadfence (agent scope) writes the XCD's dirty L2 back to L3 before the
// arrival atomic. Acquire: thread0's post-gate __threadfence invalidates
// L1/L2 so post-barrier loads see other XCDs' data.
__device__ inline void grid_sync(unsigned* cnt, unsigned* gate) {
    __syncthreads();
    if (threadIdx.x == 0) {
        __threadfence();
        unsigned arrived = __hip_atomic_fetch_add(
            cnt, 1u, __ATOMIC_ACQ_REL, __HIP_MEMORY_SCOPE_AGENT) + 1u;
        if (arrived == (unsigned)NBLK) {
            __hip_atomic_store(gate, 1u, __ATOMIC_RELEASE,
                               __HIP_MEMORY_SCOPE_AGENT);
        } else {
            while (__hip_atomic_load(gate, __ATOMIC_ACQUIRE,
                                     __HIP_MEMORY_SCOPE_AGENT) == 0u)
                __builtin_amdgcn_s_sleep(2);
        }
        __threadfence();
    }
    __syncthreads();
}

// ======================= fused cooperative kernel =======================
__global__ __launch_bounds__(256, 4) void fused_ssd(
    const float* __restrict__ X, const float* __restrict__ delta,
    const float* __restrict__ Bm, const float* __restrict__ Cm,
    const float* __restrict__ A_log,
    ushort* __restrict__ Hbuf, float* __restrict__ Dchunk,
    float* __restrict__ Y, float* __restrict__ Hlast,
    unsigned* __restrict__ bar)
{
    __shared__ __align__(16) ushort sXt[4096];   // X^T [p][tau]   (A -> C)
    __shared__ __align__(16) ushort sB [4096];   // B [t][n]       (A -> C); C: S
    __shared__ __align__(16) ushort sH [4096];   // A: B^T -> Hend stage; C: Hstart
    __shared__ float sVec[256];                  // sa | sb | Lambda | wf

    const int tid  = threadIdx.x, lane = tid & 63, w = tid >> 6;
    const int quad = lane >> 4,   l16  = lane & 15;
    const int blk = blockIdx.x;               // ((b*NC)+c)*H + h  (h fastest)
    const int h   = blk & (H - 1);
    const int c   = (blk >> 4) & (NC - 1);
    const int b   = blk >> 9;
    const int t0  = c * L;
    const int chunkid = (b * H + h) * NC + c;

    // ================= Phase A =================
    {   // B^T [n][tau] swizzled -> sH (dead until phase C Hstart DMA)
        const float* gB = Bm + ((size_t)b * T + t0) * N;
        #pragma unroll
        for (int i = 0; i < 8; ++i) {
            int tau = (w * 8 + i) * 2;
            *(unsigned*)&sH[swz(lane, tau)] =
                pack2(gB[(size_t)tau * N + lane], gB[(size_t)(tau + 1) * N + lane]);
        }
    }
    {   // X^T [p][tau] swizzled
        const float* gX = X + (((size_t)b * T + t0) * H + h) * P;
        #pragma unroll
        for (int i = 0; i < 8; ++i) {
            int tau = w * 16 + 2 * i;
            *(unsigned*)&sXt[swz(lane, tau)] =
                pack2(gX[(size_t)tau * (H * P) + lane],
                      gX[(size_t)(tau + 1) * (H * P) + lane]);
        }
    }
    {   // B [t][n] bf16 swizzled (persists to phase C; fp32 src L2-hot)
        const float4* gB4 = (const float4*)(Bm + ((size_t)b * T + t0) * N);
        #pragma unroll
        for (int r = 0; r < 4; ++r) {
            int idx = r * 256 + tid, t = idx >> 4, n4 = idx & 15;
            int g = n4 >> 1, half = n4 & 1;
            int off = t * 64 + (((g ^ (t & 7))) << 3) + half * 4;
            float4 vb = gB4[idx];
            *(uint2*)&sB[off] = make_uint2(pack2(vb.x, vb.y), pack2(vb.z, vb.w));
        }
    }
    if (w == 0) {   // cumsum + per-chunk vectors (kept in LDS)
        float dl = delta[((size_t)b * T + t0 + lane) * H + h];
        float s = -__expf(A_log[h]) * dl;
        #pragma unroll
        for (int off = 1; off < 64; off <<= 1) {
            float u = __shfl_up(s, off, 64);
            if (lane >= off) s += u;
        }
        float sL  = __shfl(s, 63, 64);
        float lnd = __logf(dl);
        sVec[192 + lane] = __expf(sL + lnd - s);   // wf
        sVec[lane]       = s;                      // sa
        sVec[64 + lane]  = lnd - s;                // sb
        sVec[128 + lane] = __expf(s);              // Lambda
        if (lane == 63) Dchunk[chunkid] = __expf(sL);
    }
    __syncthreads();

    // Hend0 strip = (w*X)^T . B   (B^T in sH, swizzled)
    f32x4 ha[4];
    #pragma unroll
    for (int j = 0; j < 4; ++j) ha[j] = (f32x4){0.f, 0.f, 0.f, 0.f};
    #pragma unroll
    for (int ks = 0; ks < 2; ++ks) {
        const int ko = ks * 32 + quad * 8;
        const int sg = (ko >> 3) ^ (l16 & 7);
        bf16x8 xa = *(const bf16x8*)&sXt[(w * 16 + l16) * 64 + sg * 8];
        union { bf16x8 v; unsigned u[4]; } xw;
        #pragma unroll
        for (int j2 = 0; j2 < 4; ++j2)
            xw.u[j2] = pack2(bf2f((ushort)xa[2*j2])   * sVec[192 + ko + 2*j2],
                             bf2f((ushort)xa[2*j2+1]) * sVec[192 + ko + 2*j2+1]);
        #pragma unroll
        for (int jn = 0; jn < 4; ++jn) {
            bf16x8 bb = *(const bf16x8*)&sH[(jn * 16 + l16) * 64 + sg * 8];
            ha[jn] = __builtin_amdgcn_mfma_f32_16x16x32_bf16(xw.v, bb, ha[jn], 0, 0, 0);
        }
    }
    __syncthreads();   // all B^T frag reads done; sH reusable
    {   // restage Hend swizzled into sH, then linear dump to Hbuf
        #pragma unroll
        for (int jn = 0; jn < 4; ++jn)
            #pragma unroll
            for (int r = 0; r < 4; ++r)
                sH[swz(w * 16 + quad * 4 + r, jn * 16 + l16)] = f2bf(ha[jn][r]);
    }
    __syncthreads();
    {
        ushort* Ht = Hbuf + (size_t)chunkid * 4096;
        #pragma unroll
        for (int i = 0; i < 2; ++i) {
            int j = i * 256 + tid;
            ((uint4*)Ht)[j] = ((const uint4*)sH)[j];
        }
    }

    grid_sync(bar + 0, bar + 1);

    // ================= Phase B: chunk scan (wave 0 of each block) =========
    if (w == 0) {
        const unsigned gid = blockIdx.x * 64u + lane;   // 65536 scan threads
        const int bh  = gid >> 11;
        const int rem = gid & 2047;
        unsigned* Hb = (unsigned*)Hbuf;
        const float* Dp = Dchunk + bh * NC;
        float hx = 0.f, hy = 0.f;
        #pragma unroll
        for (int half = 0; half < 2; ++half) {   // 16-chunk batches (VGPR)
            unsigned v[16];
            #pragma unroll
            for (int i = 0; i < 16; ++i)
                v[i] = Hb[(size_t)(bh * NC + half * 16 + i) * 2048 + rem];
            #pragma unroll
            for (int i = 0; i < 16; ++i) {
                const float lo = bf2f((ushort)(v[i] & 0xffffu));
                const float hi = bf2f((ushort)(v[i] >> 16));
                v[i] = pack2(hx, hy);           // Hstart for this chunk
                const float D = Dp[half * 16 + i];
                hx = D * hx + lo;
                hy = D * hy + hi;
            }
            #pragma unroll
            for (int i = 0; i < 16; ++i)
                Hb[(size_t)(bh * NC + half * 16 + i) * 2048 + rem] = v[i];
        }
        // un-swizzle for Hlast [b,h,p,n]
        const int p   = rem >> 5, w32 = rem & 31;
        const int g   = (w32 >> 2) ^ (p & 7);
        const int n0  = (g << 3) + ((w32 & 3) << 1);
        *(float2*)&Hlast[(size_t)bh * 4096 + p * 64 + n0] = make_float2(hx, hy);
    }

    grid_sync(bar + 2, bar + 3);

    // ================= Phase C =================
    {   // DMA Hstart -> sH (2KB per wave)
        const char* gsrc = (const char*)(Hbuf + (size_t)chunkid * 4096)
                           + w * 2048 + lane * 16;
        char* ldst = (char*)sH + w * 2048;
        dma16(gsrc, ldst);
        dma16(gsrc + 1024, ldst + 1024);
    }
    // C A-operand frags (row t = t0+w*16+l16, k = ks*32+quad*8..+7) from fp32
    bf16x8 cfrag[2];
    {
        const float* gC = Cm + ((size_t)b * T + t0 + w * 16 + l16) * N + quad * 8;
        #pragma unroll
        for (int ks = 0; ks < 2; ++ks) {
            float4 c0 = *(const float4*)&gC[ks * 32];
            float4 c1 = *(const float4*)&gC[ks * 32 + 4];
            union { bf16x8 v; unsigned u[4]; } cf;
            cf.u[0] = pack2(c0.x, c0.y); cf.u[1] = pack2(c0.z, c0.w);
            cf.u[2] = pack2(c1.x, c1.y); cf.u[3] = pack2(c1.z, c1.w);
            cfrag[ks] = cf.v;
        }
    }
    __syncthreads();   // DMA + cfrag loads drained

    // G strip = C . B^T  (rows t in [16w,16w+16), K=n); B-operand from sB
    f32x4 g4[4];
    #pragma unroll
    for (int j = 0; j < 4; ++j) g4[j] = (f32x4){0.f, 0.f, 0.f, 0.f};
    #pragma unroll
    for (int ks = 0; ks < 2; ++ks) {
        const int ko = ks * 32 + quad * 8;
        const int sg = (ko >> 3) ^ (l16 & 7);
        #pragma unroll
        for (int jt = 0; jt < 4; ++jt) {
            bf16x8 bfr = *(const bf16x8*)&sB[(jt * 16 + l16) * 64 + sg * 8];
            g4[jt] = __builtin_amdgcn_mfma_f32_16x16x32_bf16(cfrag[ks], bfr, g4[jt], 0, 0, 0);
        }
    }
    __syncthreads();   // all G reads of sB done before S overwrites it

    // S strip -> sB alias (swizzled [t][tau])
    #pragma unroll
    for (int jt = 0; jt < 4; ++jt) {
        const int tau = jt * 16 + l16;
        const float sbv = sVec[64 + tau];
        #pragma unroll
        for (int r = 0; r < 4; ++r) {
            const int t = w * 16 + quad * 4 + r;
            float arg = (tau <= t) ? (sVec[t] + sbv) : -80.0f;
            sB[swz(t, tau)] = f2bf(__expf(arg) * g4[jt][r]);
        }
    }
    __syncthreads();

    // Yint = S . Xt  and  acc = C . Hstart
    f32x4 ya[4], acc[4];
    #pragma unroll
    for (int j = 0; j < 4; ++j) {
        ya[j]  = (f32x4){0.f, 0.f, 0.f, 0.f};
        acc[j] = (f32x4){0.f, 0.f, 0.f, 0.f};
    }
    #pragma unroll
    for (int ks = 0; ks < 2; ++ks) {
        const int ko = ks * 32 + quad * 8;
        const int sg = (ko >> 3) ^ (l16 & 7);
        bf16x8 sa = *(const bf16x8*)&sB[(w * 16 + l16) * 64 + sg * 8];
        #pragma unroll
        for (int jp = 0; jp < 4; ++jp) {
            bf16x8 xb = *(const bf16x8*)&sXt[(jp * 16 + l16) * 64 + sg * 8];
            bf16x8 hb = *(const bf16x8*)&sH [(jp * 16 + l16) * 64 + sg * 8];
            ya[jp]  = __builtin_amdgcn_mfma_f32_16x16x32_bf16(sa, xb, ya[jp], 0, 0, 0);
            acc[jp] = __builtin_amdgcn_mfma_f32_16x16x32_bf16(cfrag[ks], hb, acc[jp], 0, 0, 0);
        }
    }

    // fused Y store
    float* Yg = Y + (((size_t)b * T + t0) * H + h) * P;
    #pragma unroll
    for (int jp = 0; jp < 4; ++jp)
        #pragma unroll
        for (int r = 0; r < 4; ++r) {
            const int t = w * 16 + quad * 4 + r;
            Yg[(size_t)t * (H * P) + jp * 16 + l16] =
                ya[jp][r] + sVec[128 + t] * acc[jp][r];
        }
}

// ======================= fallback: round-9 three-kernel path ==============
__global__ __launch_bounds__(256, 4) void ka_prep(
    const float* __restrict__ X, const float* __restrict__ delta,
    const float* __restrict__ Bm, const float* __restrict__ Cm,
    const float* __restrict__ A_log,
    ushort* __restrict__ Xtg, ushort* __restrict__ Hbuf,
    ushort* __restrict__ Bbf, ushort* __restrict__ Cbf,
    float* __restrict__ Vec, float* __restrict__ Dchunk)
{
    __shared__ __align__(16) ushort sXt[4096];
    __shared__ __align__(16) ushort sBt[64 * LSB];
    __shared__ float sWf[64];

    const int tid  = threadIdx.x, lane = tid & 63, w = tid >> 6;
    const int quad = lane >> 4,   l16  = lane & 15;
    const int blk = blockIdx.x;
    const int h   = blk & (H - 1);
    const int c   = (blk >> 4) & (NC - 1);
    const int b   = blk >> 9;
    const int t0  = c * L;
    const int chunkid = (b * H + h) * NC + c;
    const int bcid    = b * NC + c;

    {
        const float* gB = Bm + ((size_t)b * T + t0) * N;
        #pragma unroll
        for (int i = 0; i < 8; ++i) {
            int tau = (w * 8 + i) * 2;
            *(unsigned*)&sBt[lane * LSB + tau] =
                pack2(gB[(size_t)tau * N + lane], gB[(size_t)(tau + 1) * N + lane]);
        }
    }
    {
        const float* gX = X + (((size_t)b * T + t0) * H + h) * P;
        #pragma unroll
        for (int i = 0; i < 8; ++i) {
            int tau = w * 16 + 2 * i;
            *(unsigned*)&sXt[swz(lane, tau)] =
                pack2(gX[(size_t)tau * (H * P) + lane],
                      gX[(size_t)(tau + 1) * (H * P) + lane]);
        }
    }
    if (h == 0) {
        const float4* gB4 = (const float4*)(Bm + ((size_t)b * T + t0) * N);
        const float4* gC4 = (const float4*)(Cm + ((size_t)b * T + t0) * N);
        ushort* Bt = Bbf + (size_t)bcid * 4096;
        ushort* Ct = Cbf + (size_t)bcid * 4096;
        #pragma unroll
        for (int r = 0; r < 4; ++r) {
            int idx = r * 256 + tid, t = idx >> 4, n4 = idx & 15;
            int g = n4 >> 1, half = n4 & 1;
            int off = t * 64 + (((g ^ (t & 7))) << 3) + half * 4;
            float4 vb = gB4[idx], vc = gC4[idx];
            *(uint2*)&Bt[off] = make_uint2(pack2(vb.x, vb.y), pack2(vb.z, vb.w));
            *(uint2*)&Ct[off] = make_uint2(pack2(vc.x, vc.y), pack2(vc.z, vc.w));
        }
    }
    if (w == 0) {
        float dl = delta[((size_t)b * T + t0 + lane) * H + h];
        float s = -__expf(A_log[h]) * dl;
        #pragma unroll
        for (int off = 1; off < 64; off <<= 1) {
            float u = __shfl_up(s, off, 64);
            if (lane >= off) s += u;
        }
        float sL  = __shfl(s, 63, 64);
        float lnd = __logf(dl);
        sWf[lane] = __expf(sL + lnd - s);
        float* vp = Vec + (size_t)chunkid * 192;
        vp[lane]       = s;
        vp[64 + lane]  = lnd - s;
        vp[128 + lane] = __expf(s);
        if (lane == 63) Dchunk[chunkid] = __expf(sL);
    }
    __syncthreads();

    f32x4 ha[4];
    #pragma unroll
    for (int j = 0; j < 4; ++j) ha[j] = (f32x4){0.f, 0.f, 0.f, 0.f};
    #pragma unroll
    for (int ks = 0; ks < 2; ++ks) {
        const int ko = ks * 32 + quad * 8;
        const int sg = (ko >> 3) ^ (l16 & 7);
        bf16x8 xa = *(const bf16x8*)&sXt[(w * 16 + l16) * 64 + sg * 8];
        union { bf16x8 v; unsigned u[4]; } xw;
        #pragma unroll
        for (int j2 = 0; j2 < 4; ++j2)
            xw.u[j2] = pack2(bf2f((ushort)xa[2*j2])   * sWf[ko + 2*j2],
                             bf2f((ushort)xa[2*j2+1]) * sWf[ko + 2*j2+1]);
        #pragma unroll
        for (int jn = 0; jn < 4; ++jn) {
            bf16x8 bb = *(const bf16x8*)&sBt[(jn * 16 + l16) * LSB + ko];
            ha[jn] = __builtin_amdgcn_mfma_f32_16x16x32_bf16(xw.v, bb, ha[jn], 0, 0, 0);
        }
    }
    {
        ushort* Xtt = Xtg + (size_t)chunkid * 4096;
        #pragma unroll
        for (int i = 0; i < 2; ++i) {
            int j = i * 256 + tid;
            ((uint4*)Xtt)[j] = ((const uint4*)sXt)[j];
        }
    }
    __syncthreads();
    {
        ushort* hst = sBt;
        #pragma unroll
        for (int jn = 0; jn < 4; ++jn)
            #pragma unroll
            for (int r = 0; r < 4; ++r)
                hst[swz(w * 16 + quad * 4 + r, jn * 16 + l16)] = f2bf(ha[jn][r]);
    }
    __syncthreads();
    {
        ushort* Ht = Hbuf + (size_t)chunkid * 4096;
        #pragma unroll
        for (int i = 0; i < 2; ++i) {
            int j = i * 256 + tid;
            ((uint4*)Ht)[j] = ((const uint4*)sBt)[j];
        }
    }
}

__global__ __launch_bounds__(256, 4) void k2_scan(
    const float* __restrict__ Dchunk, ushort* __restrict__ Hbuf,
    float* __restrict__ Hlast)
{
    const unsigned gid = blockIdx.x * 256u + threadIdx.x;
    const int bh  = gid >> 11;
    const int rem = gid & 2047;
    unsigned* Hb = (unsigned*)Hbuf;
    unsigned v[NC];
    #pragma unroll
    for (int cc = 0; cc < NC; ++cc)
        v[cc] = Hb[(size_t)(bh * NC + cc) * 2048 + rem];
    float hx = 0.f, hy = 0.f;
    #pragma unroll
    for (int cc = 0; cc < NC; ++cc) {
        const float lo = bf2f((ushort)(v[cc] & 0xffffu));
        const float hi = bf2f((ushort)(v[cc] >> 16));
        v[cc] = pack2(hx, hy);
        const float D = Dchunk[bh * NC + cc];
        hx = D * hx + lo;
        hy = D * hy + hi;
    }
    #pragma unroll
    for (int cc = 0; cc < NC; ++cc)
        Hb[(size_t)(bh * NC + cc) * 2048 + rem] = v[cc];
    const int p   = rem >> 5, w32 = rem & 31;
    const int g   = (w32 >> 2) ^ (p & 7);
    const int n0  = (g << 3) + ((w32 & 3) << 1);
    *(float2*)&Hlast[(size_t)bh * 4096 + p * 64 + n0] = make_float2(hx, hy);
}

__global__ __launch_bounds__(256, 4) void k3_y(
    const ushort* __restrict__ Xtg, const ushort* __restrict__ Bbf,
    const ushort* __restrict__ Cbf, const float* __restrict__ Vec,
    const ushort* __restrict__ Hbuf, float* __restrict__ Y)
{
    __shared__ __align__(16) ushort sC [4096];
    __shared__ __align__(16) ushort sB [4096];
    __shared__ __align__(16) ushort sXt[4096];
    __shared__ __align__(16) ushort sH [4096];
    __shared__ float sVec[192];

    const int tid  = threadIdx.x, lane = tid & 63, w = tid >> 6;
    const int quad = lane >> 4,   l16  = lane & 15;
    const int blk = blockIdx.x;
    const int h   = blk & (H - 1);
    const int c   = (blk >> 4) & (NC - 1);
    const int b   = blk >> 9;
    const int t0  = c * L;
    const int chunkid = (b * H + h) * NC + c;
    const int bcid    = b * NC + c;

    {
        const ushort* gsrc;
        ushort* ldst;
        if      (w == 0) { gsrc = Cbf + (size_t)bcid * 4096;    ldst = sC;  }
        else if (w == 1) { gsrc = Bbf + (size_t)bcid * 4096;    ldst = sB;  }
        else if (w == 2) { gsrc = Xtg + (size_t)chunkid * 4096; ldst = sXt; }
        else             { gsrc = Hbuf + (size_t)chunkid * 4096; ldst = sH; }
        const char* g = (const char*)gsrc + lane * 16;
        #pragma unroll
        for (int i = 0; i < 8; ++i)
            dma16(g + i * 1024, (char*)ldst + i * 1024);
        if (w == 0) {
            const float* vp = Vec + (size_t)chunkid * 192;
            dma4(vp + lane,       sVec);
            dma4(vp + 64 + lane,  sVec + 64);
            dma4(vp + 128 + lane, sVec + 128);
        }
    }
    __syncthreads();

    f32x4 g4[4];
    #pragma unroll
    for (int j = 0; j < 4; ++j) g4[j] = (f32x4){0.f, 0.f, 0.f, 0.f};
    #pragma unroll
    for (int ks = 0; ks < 2; ++ks) {
        const int ko = ks * 32 + quad * 8;
        const int sg = (ko >> 3) ^ (l16 & 7);
        bf16x8 af = *(const bf16x8*)&sC[(w * 16 + l16) * 64 + sg * 8];
        #pragma unroll
        for (int jt = 0; jt < 4; ++jt) {
            bf16x8 bfr = *(const bf16x8*)&sB[(jt * 16 + l16) * 64 + sg * 8];
            g4[jt] = __builtin_amdgcn_mfma_f32_16x16x32_bf16(af, bfr, g4[jt], 0, 0, 0);
        }
    }
    __syncthreads();

    #pragma unroll
    for (int jt = 0; jt < 4; ++jt) {
        const int tau = jt * 16 + l16;
        const float sbv = sVec[64 + tau];
        #pragma unroll
        for (int r = 0; r < 4; ++r) {
            const int t = w * 16 + quad * 4 + r;
            float arg = (tau <= t) ? (sVec[t] + sbv) : -80.0f;
            sB[swz(t, tau)] = f2bf(__expf(arg) * g4[jt][r]);
        }
    }
    __syncthreads();

    f32x4 ya[4], acc[4];
    #pragma unroll
    for (int j = 0; j < 4; ++j) {
        ya[j]  = (f32x4){0.f, 0.f, 0.f, 0.f};
        acc[j] = (f32x4){0.f, 0.f, 0.f, 0.f};
    }
    #pragma unroll
    for (int ks = 0; ks < 2; ++ks) {
        const int ko = ks * 32 + quad * 8;
        const int sg = (ko >> 3) ^ (l16 & 7);
        bf16x8 sa = *(const bf16x8*)&sB[(w * 16 + l16) * 64 + sg * 8];
        bf16x8 ca = *(const bf16x8*)&sC[(w * 16 + l16) * 64 + sg * 8];
        #pragma unroll
        for (int jp = 0; jp < 4; ++jp) {
            bf16x8 xb = *(const bf16x8*)&sXt[(jp * 16 + l16) * 64 + sg * 8];
            bf16x8 hb = *(const bf16x8*)&sH [(jp * 16 + l16) * 64 + sg * 8];
            ya[jp]  = __builtin_amdgcn_mfma_f32_16x16x32_bf16(sa, xb, ya[jp], 0, 0, 0);
            acc[jp] = __builtin_amdgcn_mfma_f32_16x16x32_bf16(ca, hb, acc[jp], 0, 0, 0);
        }
    }

    float* Yg = Y + (((size_t)b * T + t0) * H + h) * P;
    #pragma unroll
    for (int jp = 0; jp < 4; ++jp)
        #pragma unroll
        for (int r = 0; r < 4; ++r) {
            const int t = w * 16 + quad * 4 + r;
            Yg[(size_t)t * (H * P) + jp * 16 + l16] =
                ya[jp][r] + sVec[128 + t] * acc[jp][r];
        }
}

// ======================= launcher =======================
extern "C" void kernel_launch(void* const* d_in, const int* in_sizes, int n_in,
                              void* d_out, int out_size, void* d_ws, size_t ws_size,
                              hipStream_t stream) {
    const float* X     = (const float*)d_in[0];
    const float* delta = (const float*)d_in[1];
    const float* Bm    = (const float*)d_in[2];
    const float* Cm    = (const float*)d_in[3];
    const float* A_log = (const float*)d_in[4];

    float* Y     = (float*)d_out;
    float* Hlast = (float*)d_out + (size_t)BSZ * T * H * P;

    char* ws = (char*)d_ws;
    unsigned* bar  = (unsigned*)ws;                        // 64 B (zeroed below)
    float*  Dchunk = (float*)(ws + 256);                   // 4 KiB
    ushort* Hbuf   = (ushort*)(ws + (1u << 13));           // 8 MiB @ +8 KiB
    // fallback-only buffers (past the fused region)
    ushort* Xtg    = (ushort*)(ws + (16u << 20));          // 8 MiB
    ushort* Bbf    = (ushort*)(ws + (24u << 20));          // 512 KiB
    ushort* Cbf    = (ushort*)(ws + (24u << 20) + (512u << 10));
    float*  Vec    = (float*)(ws + (25u << 20));           // 768 KiB

    hipMemsetAsync(bar, 0, 64, stream);   // barrier counters/gates

    void* args[] = {(void*)&X, (void*)&delta, (void*)&Bm, (void*)&Cm,
                    (void*)&A_log, (void*)&Hbuf, (void*)&Dchunk,
                    (void*)&Y, (void*)&Hlast, (void*)&bar};
    hipError_t e = hipLaunchCooperativeKernel((void*)fused_ssd, dim3(NBLK),
                                              dim3(256), args, 0, stream);
    if (e != hipSuccess) {
        (void)hipGetLastError();   // clear error state; take proven 3-kernel path
        ka_prep<<<NBLK, 256, 0, stream>>>(X, delta, Bm, Cm, A_log,
                                          Xtg, Hbuf, Bbf, Cbf, Vec, Dchunk);
        k2_scan<<<256, 256, 0, stream>>>(Dchunk, Hbuf, Hlast);
        k3_y<<<NBLK, 256, 0, stream>>>(Xtg, Bbf, Cbf, Vec, Hbuf, Y);
    }
}

// Round 3
// 96.402 us; speedup vs baseline: 3.5551x; 3.5551x over previous
//
#include <hip/hip_runtime.h>

// Round 12: REVERT to the proven round-9 three-kernel pipeline (97.3 us,
// passed). Round 10/11 fusion post-mortem: cooperative fusion ran but the
// grid barriers cost ~115 us each (ACQUIRE agent-scope spin loads emit
// buffer_inv per poll -> L2 invalidate storm; MfmaUtil 0.3%, VALUBusy 2.2%).
// Timeline decomposition shows the three kernels total only ~6 us of GPU
// time (~= 34 MB minimum HBM traffic at 6.3 TB/s); the measured dur_us is
// dominated by ~91 us of harness workspace re-poison fills per iteration.
// Fusion has no headroom worth the risk; this is the known-good optimum.
//
//   KA: per (b,h,c): build swizzled bf16 tiles (Xt [p][tau]) + cumsum vectors,
//       compute Hend0=(w.X)^T.B, dump Xt/Hend/Bbf/Cbf/Vec to ws.
//   K2: 32-chunk scan over bf16 pairs (layout-agnostic) -> Hstart + Hlast.
//   K3: stage C,B,Xt,Hstart via __builtin_amdgcn_global_load_lds (width 16,
//       1 KB/instr) -> G=C.B^T -> S=mask*exp*G (alias over B) ->
//       Yint=S.Xt + acc=C.Hst -> Y = Yint + Lam*acc (single store).
// Tile format: 64x64 bf16, UNPADDED, 16B-group XOR swizzle:
//   elem(row,col) stored at row*64 + ((col>>3 ^ (row&7))<<3) + (col&7).
//   -> ds_read_b128 frag reads hit 8 bank-groups x2 lanes (2-way = free, m136)
//   -> lane-contiguous rows, so global_load_lds DMA works (no padding allowed).
// MFMA 16x16x32 bf16: A m=lane&15,k=quad*8+j; B n=lane&15,k=quad*8+j;
//                     D col=lane&15, row=quad*4+reg.
// All MFMA frag rows are == l16 (mod 8), so swizzle group = (ko>>3)^(l16&7).

constexpr int BSZ = 2, T = 2048, H = 16, P = 64, N = 64;
constexpr int L = 64, NC = T / L;   // 32 chunks
constexpr int LSB = 72;             // padded stride for KA-internal B^T only

using bf16x8 = __attribute__((ext_vector_type(8))) short;
using f32x4  = __attribute__((ext_vector_type(4))) float;

__device__ inline ushort f2bf(float f) {
    unsigned u = __float_as_uint(f);
    u += 0x7FFFu + ((u >> 16) & 1u);
    return (ushort)(u >> 16);
}
__device__ inline unsigned pack2(float a, float b) {
    return (unsigned)f2bf(a) | ((unsigned)f2bf(b) << 16);
}
__device__ inline float bf2f(ushort h) {
    return __uint_as_float(((unsigned)h) << 16);
}
__device__ inline int swz(int row, int col) {   // element offset in 64x64 tile
    return row * 64 + ((((col >> 3) ^ (row & 7))) << 3) + (col & 7);
}

typedef __attribute__((address_space(3))) unsigned int       lds_u32;
typedef const __attribute__((address_space(1))) unsigned int glb_u32;
__device__ inline void dma16(const void* g, void* l) {   // 16B/lane -> 1KB/wave
    __builtin_amdgcn_global_load_lds((glb_u32*)g, (lds_u32*)l, 16, 0, 0);
}
__device__ inline void dma4(const void* g, void* l) {    // 4B/lane -> 256B/wave
    __builtin_amdgcn_global_load_lds((glb_u32*)g, (lds_u32*)l, 4, 0, 0);
}

// ---------------- KA: prep + chunk-local end state ----------------
__global__ __launch_bounds__(256, 4) void ka_prep(
    const float* __restrict__ X, const float* __restrict__ delta,
    const float* __restrict__ Bm, const float* __restrict__ Cm,
    const float* __restrict__ A_log,
    ushort* __restrict__ Xtg, ushort* __restrict__ Hbuf,
    ushort* __restrict__ Bbf, ushort* __restrict__ Cbf,
    float* __restrict__ Vec, float* __restrict__ Dchunk)
{
    __shared__ __align__(16) ushort sXt[4096];       // [p][tau] swizzled
    __shared__ __align__(16) ushort sBt[64 * LSB];   // [n][tau] padded (internal)
    __shared__ float sWf[64];

    const int tid  = threadIdx.x, lane = tid & 63, w = tid >> 6;
    const int quad = lane >> 4,   l16  = lane & 15;
    const int blk = blockIdx.x;               // ((b*NC)+c)*H + h  (h fastest)
    const int h   = blk & (H - 1);
    const int c   = (blk >> 4) & (NC - 1);
    const int b   = blk >> 9;
    const int t0  = c * L;
    const int chunkid = (b * H + h) * NC + c;
    const int bcid    = b * NC + c;

    {   // B^T [n][tau] (padded, KA-internal)
        const float* gB = Bm + ((size_t)b * T + t0) * N;
        #pragma unroll
        for (int i = 0; i < 8; ++i) {
            int tau = (w * 8 + i) * 2;
            *(unsigned*)&sBt[lane * LSB + tau] =
                pack2(gB[(size_t)tau * N + lane], gB[(size_t)(tau + 1) * N + lane]);
        }
    }
    {   // X^T [p][tau] swizzled
        const float* gX = X + (((size_t)b * T + t0) * H + h) * P;
        #pragma unroll
        for (int i = 0; i < 8; ++i) {
            int tau = w * 16 + 2 * i;
            *(unsigned*)&sXt[swz(lane, tau)] =
                pack2(gX[(size_t)tau * (H * P) + lane],
                      gX[(size_t)(tau + 1) * (H * P) + lane]);
        }
    }
    if (h == 0) {   // dump B,C bf16 swizzled tiles (once per (b,c))
        const float4* gB4 = (const float4*)(Bm + ((size_t)b * T + t0) * N);
        const float4* gC4 = (const float4*)(Cm + ((size_t)b * T + t0) * N);
        ushort* Bt = Bbf + (size_t)bcid * 4096;
        ushort* Ct = Cbf + (size_t)bcid * 4096;
        #pragma unroll
        for (int r = 0; r < 4; ++r) {
            int idx = r * 256 + tid, t = idx >> 4, n4 = idx & 15;
            int g = n4 >> 1, half = n4 & 1;
            int off = t * 64 + (((g ^ (t & 7))) << 3) + half * 4;
            float4 vb = gB4[idx], vc = gC4[idx];
            *(uint2*)&Bt[off] = make_uint2(pack2(vb.x, vb.y), pack2(vb.z, vb.w));
            *(uint2*)&Ct[off] = make_uint2(pack2(vc.x, vc.y), pack2(vc.z, vc.w));
        }
    }
    if (w == 0) {   // cumsum + vector dumps
        float dl = delta[((size_t)b * T + t0 + lane) * H + h];
        float s = -__expf(A_log[h]) * dl;
        #pragma unroll
        for (int off = 1; off < 64; off <<= 1) {
            float u = __shfl_up(s, off, 64);
            if (lane >= off) s += u;
        }
        float sL  = __shfl(s, 63, 64);
        float lnd = __logf(dl);
        sWf[lane] = __expf(sL + lnd - s);
        float* vp = Vec + (size_t)chunkid * 192;
        vp[lane]       = s;            // sa
        vp[64 + lane]  = lnd - s;      // sb
        vp[128 + lane] = __expf(s);    // Lambda
        if (lane == 63) Dchunk[chunkid] = __expf(sL);
    }
    __syncthreads();

    // Hend0 strip = (w*X)^T . B
    f32x4 ha[4];
    #pragma unroll
    for (int j = 0; j < 4; ++j) ha[j] = (f32x4){0.f, 0.f, 0.f, 0.f};
    #pragma unroll
    for (int ks = 0; ks < 2; ++ks) {
        const int ko = ks * 32 + quad * 8;
        const int sg = (ko >> 3) ^ (l16 & 7);
        bf16x8 xa = *(const bf16x8*)&sXt[(w * 16 + l16) * 64 + sg * 8];
        union { bf16x8 v; unsigned u[4]; } xw;
        #pragma unroll
        for (int j2 = 0; j2 < 4; ++j2)
            xw.u[j2] = pack2(bf2f((ushort)xa[2*j2])   * sWf[ko + 2*j2],
                             bf2f((ushort)xa[2*j2+1]) * sWf[ko + 2*j2+1]);
        #pragma unroll
        for (int jn = 0; jn < 4; ++jn) {
            bf16x8 bb = *(const bf16x8*)&sBt[(jn * 16 + l16) * LSB + ko];
            ha[jn] = __builtin_amdgcn_mfma_f32_16x16x32_bf16(xw.v, bb, ha[jn], 0, 0, 0);
        }
    }

    // dump Xt tile (linear copy; sXt fully written since pre-MFMA barrier)
    {
        ushort* Xtt = Xtg + (size_t)chunkid * 4096;
        #pragma unroll
        for (int i = 0; i < 2; ++i) {
            int j = i * 256 + tid;
            ((uint4*)Xtt)[j] = ((const uint4*)sXt)[j];
        }
    }
    __syncthreads();   // all sBt frag reads done
    // restage Hend swizzled into sBt area (unpadded addressing)
    {
        ushort* hst = sBt;
        #pragma unroll
        for (int jn = 0; jn < 4; ++jn)
            #pragma unroll
            for (int r = 0; r < 4; ++r)
                hst[swz(w * 16 + quad * 4 + r, jn * 16 + l16)] = f2bf(ha[jn][r]);
    }
    __syncthreads();
    {
        ushort* Ht = Hbuf + (size_t)chunkid * 4096;
        #pragma unroll
        for (int i = 0; i < 2; ++i) {
            int j = i * 256 + tid;
            ((uint4*)Ht)[j] = ((const uint4*)sBt)[j];
        }
    }
}

// ---------------- K2: chunk scan over bf16 pairs ----------------
__global__ __launch_bounds__(256, 4) void k2_scan(
    const float* __restrict__ Dchunk, ushort* __restrict__ Hbuf,
    float* __restrict__ Hlast)
{
    const unsigned gid = blockIdx.x * 256u + threadIdx.x;   // 65536
    const int bh  = gid >> 11;
    const int rem = gid & 2047;
    unsigned* Hb = (unsigned*)Hbuf;
    unsigned v[NC];
    #pragma unroll
    for (int cc = 0; cc < NC; ++cc)
        v[cc] = Hb[(size_t)(bh * NC + cc) * 2048 + rem];
    float hx = 0.f, hy = 0.f;
    #pragma unroll
    for (int cc = 0; cc < NC; ++cc) {
        const float lo = bf2f((ushort)(v[cc] & 0xffffu));
        const float hi = bf2f((ushort)(v[cc] >> 16));
        v[cc] = pack2(hx, hy);              // Hstart for chunk cc
        const float D = Dchunk[bh * NC + cc];
        hx = D * hx + lo;
        hy = D * hy + hi;
    }
    #pragma unroll
    for (int cc = 0; cc < NC; ++cc)
        Hb[(size_t)(bh * NC + cc) * 2048 + rem] = v[cc];
    // un-swizzle for Hlast [b,h,p,n]
    const int p   = rem >> 5, w32 = rem & 31;
    const int g   = (w32 >> 2) ^ (p & 7);
    const int n0  = (g << 3) + ((w32 & 3) << 1);
    *(float2*)&Hlast[(size_t)bh * 4096 + p * 64 + n0] = make_float2(hx, hy);
}

// ---------------- K3: Y = Yint + Lambda * C . Hstart ----------------
__global__ __launch_bounds__(256, 4) void k3_y(
    const ushort* __restrict__ Xtg, const ushort* __restrict__ Bbf,
    const ushort* __restrict__ Cbf, const float* __restrict__ Vec,
    const ushort* __restrict__ Hbuf, float* __restrict__ Y)
{
    __shared__ __align__(16) ushort sC [4096];   // C [t][n]
    __shared__ __align__(16) ushort sB [4096];   // B [tau][n]; then S [t][tau]
    __shared__ __align__(16) ushort sXt[4096];   // Xt [p][tau]
    __shared__ __align__(16) ushort sH [4096];   // Hstart [p][n]
    __shared__ float sVec[192];                  // sa | sb | Lambda

    const int tid  = threadIdx.x, lane = tid & 63, w = tid >> 6;
    const int quad = lane >> 4,   l16  = lane & 15;
    const int blk = blockIdx.x;
    const int h   = blk & (H - 1);
    const int c   = (blk >> 4) & (NC - 1);
    const int b   = blk >> 9;
    const int t0  = c * L;
    const int chunkid = (b * H + h) * NC + c;
    const int bcid    = b * NC + c;

    // DMA staging: wave w pulls one 8 KB tile (8 x 1 KB instrs)
    {
        const ushort* gsrc;
        ushort* ldst;
        if      (w == 0) { gsrc = Cbf + (size_t)bcid * 4096;    ldst = sC;  }
        else if (w == 1) { gsrc = Bbf + (size_t)bcid * 4096;    ldst = sB;  }
        else if (w == 2) { gsrc = Xtg + (size_t)chunkid * 4096; ldst = sXt; }
        else             { gsrc = Hbuf + (size_t)chunkid * 4096; ldst = sH; }
        const char* g = (const char*)gsrc + lane * 16;
        #pragma unroll
        for (int i = 0; i < 8; ++i)
            dma16(g + i * 1024, (char*)ldst + i * 1024);
        if (w == 0) {
            const float* vp = Vec + (size_t)chunkid * 192;
            dma4(vp + lane,       sVec);
            dma4(vp + 64 + lane,  sVec + 64);
            dma4(vp + 128 + lane, sVec + 128);
        }
    }
    __syncthreads();

    // G strip = C . B^T  (rows t in [16w,16w+16), K=n)
    f32x4 g4[4];
    #pragma unroll
    for (int j = 0; j < 4; ++j) g4[j] = (f32x4){0.f, 0.f, 0.f, 0.f};
    #pragma unroll
    for (int ks = 0; ks < 2; ++ks) {
        const int ko = ks * 32 + quad * 8;
        const int sg = (ko >> 3) ^ (l16 & 7);
        bf16x8 af = *(const bf16x8*)&sC[(w * 16 + l16) * 64 + sg * 8];
        #pragma unroll
        for (int jt = 0; jt < 4; ++jt) {
            bf16x8 bfr = *(const bf16x8*)&sB[(jt * 16 + l16) * 64 + sg * 8];
            g4[jt] = __builtin_amdgcn_mfma_f32_16x16x32_bf16(af, bfr, g4[jt], 0, 0, 0);
        }
    }
    __syncthreads();   // all G reads of sB done before S overwrites it

    // S strip -> sB alias (swizzled [t][tau])
    #pragma unroll
    for (int jt = 0; jt < 4; ++jt) {
        const int tau = jt * 16 + l16;
        const float sbv = sVec[64 + tau];
        #pragma unroll
        for (int r = 0; r < 4; ++r) {
            const int t = w * 16 + quad * 4 + r;
            float arg = (tau <= t) ? (sVec[t] + sbv) : -80.0f;
            sB[swz(t, tau)] = f2bf(__expf(arg) * g4[jt][r]);
        }
    }
    __syncthreads();

    // Yint = S . Xt  and  acc = C . Hstart
    f32x4 ya[4], acc[4];
    #pragma unroll
    for (int j = 0; j < 4; ++j) {
        ya[j]  = (f32x4){0.f, 0.f, 0.f, 0.f};
        acc[j] = (f32x4){0.f, 0.f, 0.f, 0.f};
    }
    #pragma unroll
    for (int ks = 0; ks < 2; ++ks) {
        const int ko = ks * 32 + quad * 8;
        const int sg = (ko >> 3) ^ (l16 & 7);
        bf16x8 sa = *(const bf16x8*)&sB[(w * 16 + l16) * 64 + sg * 8];
        bf16x8 ca = *(const bf16x8*)&sC[(w * 16 + l16) * 64 + sg * 8];
        #pragma unroll
        for (int jp = 0; jp < 4; ++jp) {
            bf16x8 xb = *(const bf16x8*)&sXt[(jp * 16 + l16) * 64 + sg * 8];
            bf16x8 hb = *(const bf16x8*)&sH [(jp * 16 + l16) * 64 + sg * 8];
            ya[jp]  = __builtin_amdgcn_mfma_f32_16x16x32_bf16(sa, xb, ya[jp], 0, 0, 0);
            acc[jp] = __builtin_amdgcn_mfma_f32_16x16x32_bf16(ca, hb, acc[jp], 0, 0, 0);
        }
    }

    // fused Y store (D-layout: 4 x 64B row segments per store)
    float* Yg = Y + (((size_t)b * T + t0) * H + h) * P;
    #pragma unroll
    for (int jp = 0; jp < 4; ++jp)
        #pragma unroll
        for (int r = 0; r < 4; ++r) {
            const int t = w * 16 + quad * 4 + r;
            Yg[(size_t)t * (H * P) + jp * 16 + l16] =
                ya[jp][r] + sVec[128 + t] * acc[jp][r];
        }
}

extern "C" void kernel_launch(void* const* d_in, const int* in_sizes, int n_in,
                              void* d_out, int out_size, void* d_ws, size_t ws_size,
                              hipStream_t stream) {
    const float* X     = (const float*)d_in[0];
    const float* delta = (const float*)d_in[1];
    const float* Bm    = (const float*)d_in[2];
    const float* Cm    = (const float*)d_in[3];
    const float* A_log = (const float*)d_in[4];

    float* Y     = (float*)d_out;
    float* Hlast = (float*)d_out + (size_t)BSZ * T * H * P;

    char* ws = (char*)d_ws;
    ushort* Hbuf = (ushort*)(ws);                          // 1024*8KB = 8 MiB
    ushort* Xtg  = (ushort*)(ws + (8u << 20));             // 8 MiB
    ushort* Bbf  = (ushort*)(ws + (16u << 20));            // 512 KiB
    ushort* Cbf  = (ushort*)(ws + (16u << 20) + (512u << 10));
    float*  Vec  = (float*)(ws + (17u << 20));             // 768 KiB
    float*  Dchunk = (float*)(ws + (18u << 20));           // 4 KiB

    const int nblk = BSZ * NC * H;   // 1024
    ka_prep<<<nblk, 256, 0, stream>>>(X, delta, Bm, Cm, A_log,
                                      Xtg, Hbuf, Bbf, Cbf, Vec, Dchunk);
    k2_scan<<<256, 256, 0, stream>>>(Dchunk, Hbuf, Hlast);
    k3_y<<<nblk, 256, 0, stream>>>(Xtg, Bbf, Cbf, Vec, Hbuf, Y);
}